// Round 11
// baseline (1825.737 us; speedup 1.0000x reference)
//
#include <hip/hip_runtime.h>
#include <hip/hip_bf16.h>

#define B_ 2
#define S_ 2048
#define H_ 4096
#define NH_ 32
#define NKV_ 8
#define D_ 128
#define WINDOW_ 1024
#define EPS_ 1e-5f
#define M_ (B_*S_)                       // 4096 rows (b*S+s)
#define NQKV_ ((NH_ + 2*NKV_) * D_)     // 6144

typedef __attribute__((ext_vector_type(8))) __bf16 bf16x8;
typedef __attribute__((ext_vector_type(4))) float f32x4;
typedef __attribute__((ext_vector_type(16))) float f32x16;

__device__ __forceinline__ unsigned short f2bf(float f) {
  union { __hip_bfloat16 h; unsigned short us; } cv;
  cv.h = __float2bfloat16(f);
  return cv.us;
}
__device__ __forceinline__ float bf2f(unsigned short u) {
  union { __hip_bfloat16 h; unsigned short us; } cv;
  cv.us = u;
  return __bfloat162float(cv.h);
}

// async global->LDS, 16B per lane. LDS dest must be wave-uniform base
// (HW adds lane*16); global src is per-lane.
__device__ __forceinline__ void gload16(const unsigned short* g, unsigned short* l) {
  __builtin_amdgcn_global_load_lds(
      (const __attribute__((address_space(1))) unsigned int*)(const void*)g,
      (__attribute__((address_space(3))) unsigned int*)(void*)l, 16, 0, 0);
}

// ---------------------------------------------------------------------------
// 1. Transpose + f32->bf16 convert: in[K][N] f32 -> out[N][K] bf16.
//    64x64 tile: float4 coalesced reads, ushort4 coalesced writes.
// ---------------------------------------------------------------------------
__global__ __launch_bounds__(256) void transpose_convert(
    const float* __restrict__ in, unsigned short* __restrict__ out, int K, int N) {
  __shared__ unsigned short t[64][72];
  const int n0 = blockIdx.x * 64, k0 = blockIdx.y * 64;
  const int tid = threadIdx.x;
  const int rr = tid >> 4, cc = (tid & 15) * 4;
  #pragma unroll
  for (int i = 0; i < 4; ++i) {
    const int r = i * 16 + rr;
    float4 v = *(const float4*)&in[(size_t)(k0 + r) * N + n0 + cc];
    t[cc + 0][r] = f2bf(v.x);
    t[cc + 1][r] = f2bf(v.y);
    t[cc + 2][r] = f2bf(v.z);
    t[cc + 3][r] = f2bf(v.w);
  }
  __syncthreads();
  #pragma unroll
  for (int i = 0; i < 4; ++i) {
    const int r = i * 16 + rr;
    ushort4 o;
    o.x = t[r][cc + 0]; o.y = t[r][cc + 1];
    o.z = t[r][cc + 2]; o.w = t[r][cc + 3];
    *(ushort4*)&out[(size_t)(n0 + r) * K + k0 + cc] = o;
  }
}

// ---------------------------------------------------------------------------
// 2. f32 -> bf16 elementwise (4/thread)
// ---------------------------------------------------------------------------
__global__ __launch_bounds__(256) void convert_bf16_kernel(
    const float* __restrict__ in, unsigned short* __restrict__ out, int n4) {
  int i = blockIdx.x * 256 + threadIdx.x;
  if (i >= n4) return;
  float4 v = ((const float4*)in)[i];
  ushort4 o;
  o.x = f2bf(v.x); o.y = f2bf(v.y); o.z = f2bf(v.z); o.w = f2bf(v.w);
  ((ushort4*)out)[i] = o;
}

// ---------------------------------------------------------------------------
// 3a. QKV GEMM: 256x256 tile, 8 waves, BK=32, 64KiB LDS -> 2 BLOCKS/CU
//     (4 waves/SIMD): cross-block overlap hides barrier drains; QKV grid
//     (384 blocks) fits one residency round (capacity 512) -> no tail round.
//     Paired-row LDS layout: [128][64] where LDS row r2 holds K-rows
//     {2r2, 2r2+1}; chunk index c = (row&1)*4 + kchunk, XOR'd with r2&7
//     (8-chunk swizzle space despite BK=32) -> 2 lanes/bank (free).
//     Counted vmcnt(4) gate, 2 phases (M-lo/M-hi) per K-tile.
// ---------------------------------------------------------------------------
template <bool OUT_BF16>
__global__ __launch_bounds__(512, 4) void gemm11(
    const unsigned short* __restrict__ A, const unsigned short* __restrict__ Bt,
    void* __restrict__ Cout, int N, int K) {
  __shared__ __align__(16) unsigned short lds[2][2][8192];  // [buf][A/B][128*64] = 64KiB
  const int tid = threadIdx.x;
  const int wave = tid >> 6, lane = tid & 63;
  const int l15 = lane & 15, l16 = lane >> 4;
  const int m0 = blockIdx.y * 256, n0 = blockIdx.x * 256;
  const int wmi = wave >> 2, wni = wave & 3;  // wave -> 128x64 output sub-tile

  // Staging sources: chunk d (16B) of the paired-row swizzled LDS image;
  // inverse-swizzle to find the global source so linear gload16 lands right.
  const unsigned short* asrc[2];
  const unsigned short* bsrc[2];
  #pragma unroll
  for (int it = 0; it < 2; ++it) {
    const int d = it * 512 + tid;          // 0..1023
    const int r2 = d >> 3, cl = d & 7;
    const int cu = cl ^ (r2 & 7);
    const int grow = 2 * r2 + (cu >> 2);   // global tile row 0..255
    const int gk = (cu & 3) * 8;           // k offset 0..24
    asrc[it] = A + (size_t)(m0 + grow) * K + gk;
    bsrc[it] = Bt + (size_t)(n0 + grow) * K + gk;
  }

  // Fragment read offsets (elements): row -> paired-row swizzled address.
  int offA[8], offB[4];
  #pragma unroll
  for (int mi = 0; mi < 8; ++mi) {
    const int row = wmi * 128 + mi * 16 + l15;
    const int r2 = row >> 1, cl = (row & 1) * 4 + l16;
    offA[mi] = r2 * 64 + (cl ^ (r2 & 7)) * 8;
  }
  #pragma unroll
  for (int ni = 0; ni < 4; ++ni) {
    const int row = wni * 64 + ni * 16 + l15;
    const int r2 = row >> 1, cl = (row & 1) * 4 + l16;
    offB[ni] = r2 * 64 + (cl ^ (r2 & 7)) * 8;
  }

  f32x4 acc[8][4];
  #pragma unroll
  for (int mi = 0; mi < 8; ++mi)
    #pragma unroll
    for (int ni = 0; ni < 4; ++ni) acc[mi][ni] = (f32x4){0.f, 0.f, 0.f, 0.f};

#define STG(buf, kt)                                                         \
  { _Pragma("unroll") for (int it = 0; it < 2; ++it) {                       \
      const int dst = it * 4096 + wave * 512;                                \
      gload16(asrc[it] + (size_t)(kt) * 32, &lds[buf][0][dst]);              \
      gload16(bsrc[it] + (size_t)(kt) * 32, &lds[buf][1][dst]);              \
    } }

#define PHASE_MFMA(MOFF)                                                     \
  asm volatile("s_waitcnt lgkmcnt(0)" ::: "memory");                         \
  __builtin_amdgcn_sched_barrier(0);                                         \
  __builtin_amdgcn_s_setprio(1);                                             \
  _Pragma("unroll") for (int i = 0; i < 4; ++i)                              \
    _Pragma("unroll") for (int j = 0; j < 4; ++j)                            \
      acc[(MOFF) + i][j] = __builtin_amdgcn_mfma_f32_16x16x32_bf16(          \
          av[i], bv[j], acc[(MOFF) + i][j], 0, 0, 0);                        \
  __builtin_amdgcn_s_setprio(0);                                             \
  __builtin_amdgcn_sched_barrier(0);

  const int nk = K >> 5;
  STG(0, 0)
  for (int t = 0; t < nk; ++t) {
    const int cur = t & 1;
    if (t + 1 < nk) {
      STG(cur ^ 1, t + 1)
      asm volatile("s_waitcnt vmcnt(4)" ::: "memory");  // tile t landed; t+1 in flight
    } else {
      asm volatile("s_waitcnt vmcnt(0)" ::: "memory");
    }
    __builtin_amdgcn_sched_barrier(0);
    __builtin_amdgcn_s_barrier();           // all waves: tile t visible
    __builtin_amdgcn_sched_barrier(0);
    const unsigned short* as = lds[cur][0];
    const unsigned short* bs = lds[cur][1];
    bf16x8 av[4], bv[4];
    // ---- phase 0: M-lo ----
    #pragma unroll
    for (int i = 0; i < 4; ++i) av[i] = *(const bf16x8*)&as[offA[i]];
    #pragma unroll
    for (int j = 0; j < 4; ++j) bv[j] = *(const bf16x8*)&bs[offB[j]];
    PHASE_MFMA(0)
    __builtin_amdgcn_s_barrier();
    // ---- phase 1: M-hi (B regs persist) ----
    #pragma unroll
    for (int i = 0; i < 4; ++i) av[i] = *(const bf16x8*)&as[offA[i + 4]];
    PHASE_MFMA(4)
    __builtin_amdgcn_s_barrier();           // all waves done reading buf[cur]
    __builtin_amdgcn_sched_barrier(0);      // next STG (into buf[cur]) stays below
  }
#undef STG
#undef PHASE_MFMA

  #pragma unroll
  for (int mi = 0; mi < 8; ++mi) {
    #pragma unroll
    for (int ni = 0; ni < 4; ++ni) {
      const int col = n0 + wni * 64 + ni * 16 + l15;
      #pragma unroll
      for (int j = 0; j < 4; ++j) {
        const int row = m0 + wmi * 128 + mi * 16 + l16 * 4 + j;
        if (OUT_BF16)
          ((unsigned short*)Cout)[(size_t)row * N + col] = f2bf(acc[mi][ni][j]);
        else
          ((float*)Cout)[(size_t)row * N + col] = acc[mi][ni][j];
      }
    }
  }
}

// ---------------------------------------------------------------------------
// 3b. Final GEMM (R10-proven, 1 exact round at 256 blocks): 256x256, BK=64,
//     double-buffered 128KiB, 4-phase interleave, chunk-XOR swizzle.
// ---------------------------------------------------------------------------
template <bool OUT_BF16>
__global__ __launch_bounds__(512) void gemm10(
    const unsigned short* __restrict__ A, const unsigned short* __restrict__ Bt,
    void* __restrict__ Cout, int N, int K) {
  __shared__ __align__(16) unsigned short lds[2][2][16384];  // [buf][A/B][256*64] = 128KiB
  const int tid = threadIdx.x;
  const int wave = tid >> 6, lane = tid & 63;
  const int l15 = lane & 15, l16 = lane >> 4;
  const int m0 = blockIdx.y * 256, n0 = blockIdx.x * 256;
  const int wmi = wave >> 2, wni = wave & 3;

  const unsigned short* asrc[4];
  const unsigned short* bsrc[4];
  #pragma unroll
  for (int it = 0; it < 4; ++it) {
    const int d = it * 512 + tid;
    const int row = d >> 3, cis = (d & 7) ^ (row & 7);
    asrc[it] = A + (size_t)(m0 + row) * K + cis * 8;
    bsrc[it] = Bt + (size_t)(n0 + row) * K + cis * 8;
  }

  int offA[2][8], offB[2][4];
  #pragma unroll
  for (int kk = 0; kk < 2; ++kk) {
    #pragma unroll
    for (int mi = 0; mi < 8; ++mi) {
      const int row = wmi * 128 + mi * 16 + l15;
      offA[kk][mi] = row * 64 + ((kk * 4 + l16) ^ (row & 7)) * 8;
    }
    #pragma unroll
    for (int ni = 0; ni < 4; ++ni) {
      const int row = wni * 64 + ni * 16 + l15;
      offB[kk][ni] = row * 64 + ((kk * 4 + l16) ^ (row & 7)) * 8;
    }
  }

  f32x4 acc[8][4];
  #pragma unroll
  for (int mi = 0; mi < 8; ++mi)
    #pragma unroll
    for (int ni = 0; ni < 4; ++ni) acc[mi][ni] = (f32x4){0.f, 0.f, 0.f, 0.f};

#define PHASE_MFMA(MOFF)                                                     \
  asm volatile("s_waitcnt lgkmcnt(0)" ::: "memory");                         \
  __builtin_amdgcn_sched_barrier(0);                                         \
  __builtin_amdgcn_s_setprio(1);                                             \
  _Pragma("unroll") for (int i = 0; i < 4; ++i)                              \
    _Pragma("unroll") for (int j = 0; j < 4; ++j)                            \
      acc[(MOFF) + i][j] = __builtin_amdgcn_mfma_f32_16x16x32_bf16(          \
          av[i], bv[j], acc[(MOFF) + i][j], 0, 0, 0);                        \
  __builtin_amdgcn_s_setprio(0);                                             \
  __builtin_amdgcn_sched_barrier(0);

  #pragma unroll
  for (int it = 0; it < 4; ++it) {
    gload16(asrc[it], &lds[0][0][it * 4096 + wave * 512]);
    gload16(bsrc[it], &lds[0][1][it * 4096 + wave * 512]);
  }
  asm volatile("s_waitcnt vmcnt(0)" ::: "memory");
  __builtin_amdgcn_sched_barrier(0);
  __builtin_amdgcn_s_barrier();

  const int nk = K >> 6;
  for (int t = 0; t < nk; ++t) {
    const int cur = t & 1, nxt = cur ^ 1;
    const unsigned short* as = lds[cur][0];
    const unsigned short* bs = lds[cur][1];
    const bool dostg = (t + 1 < nk);
    const size_t ko = (size_t)(t + 1) * 64;
    bf16x8 av[4], bv[4];

    #pragma unroll
    for (int i = 0; i < 4; ++i) av[i] = *(const bf16x8*)&as[offA[0][i]];
    #pragma unroll
    for (int j = 0; j < 4; ++j) bv[j] = *(const bf16x8*)&bs[offB[0][j]];
    if (dostg) {
      gload16(asrc[0] + ko, &lds[nxt][0][0 * 4096 + wave * 512]);
      gload16(asrc[1] + ko, &lds[nxt][0][1 * 4096 + wave * 512]);
    }
    __builtin_amdgcn_sched_barrier(0);
    __builtin_amdgcn_s_barrier();
    PHASE_MFMA(0)
    __builtin_amdgcn_s_barrier();

    #pragma unroll
    for (int i = 0; i < 4; ++i) av[i] = *(const bf16x8*)&as[offA[0][i + 4]];
    if (dostg) {
      gload16(asrc[2] + ko, &lds[nxt][0][2 * 4096 + wave * 512]);
      gload16(asrc[3] + ko, &lds[nxt][0][3 * 4096 + wave * 512]);
    }
    __builtin_amdgcn_sched_barrier(0);
    __builtin_amdgcn_s_barrier();
    PHASE_MFMA(4)
    __builtin_amdgcn_s_barrier();

    #pragma unroll
    for (int i = 0; i < 4; ++i) av[i] = *(const bf16x8*)&as[offA[1][i]];
    #pragma unroll
    for (int j = 0; j < 4; ++j) bv[j] = *(const bf16x8*)&bs[offB[1][j]];
    if (dostg) {
      gload16(bsrc[0] + ko, &lds[nxt][1][0 * 4096 + wave * 512]);
      gload16(bsrc[1] + ko, &lds[nxt][1][1 * 4096 + wave * 512]);
    }
    __builtin_amdgcn_sched_barrier(0);
    __builtin_amdgcn_s_barrier();
    PHASE_MFMA(0)
    __builtin_amdgcn_s_barrier();

    #pragma unroll
    for (int i = 0; i < 4; ++i) av[i] = *(const bf16x8*)&as[offA[1][i + 4]];
    if (dostg) {
      gload16(bsrc[2] + ko, &lds[nxt][1][2 * 4096 + wave * 512]);
      gload16(bsrc[3] + ko, &lds[nxt][1][3 * 4096 + wave * 512]);
    }
    __builtin_amdgcn_sched_barrier(0);
    __builtin_amdgcn_s_barrier();
    PHASE_MFMA(4)
    asm volatile("s_waitcnt vmcnt(0)" ::: "memory");
    __builtin_amdgcn_sched_barrier(0);
    __builtin_amdgcn_s_barrier();
  }
#undef PHASE_MFMA

  #pragma unroll
  for (int mi = 0; mi < 8; ++mi) {
    #pragma unroll
    for (int ni = 0; ni < 4; ++ni) {
      const int col = n0 + wni * 64 + ni * 16 + l15;
      #pragma unroll
      for (int j = 0; j < 4; ++j) {
        const int row = m0 + wmi * 128 + mi * 16 + l16 * 4 + j;
        if (OUT_BF16)
          ((unsigned short*)Cout)[(size_t)row * N + col] = f2bf(acc[mi][ni][j]);
        else
          ((float*)Cout)[(size_t)row * N + col] = acc[mi][ni][j];
      }
    }
  }
}

// ---------------------------------------------------------------------------
// 4. Per-head RMSNorm + RoPE. One block per (b,s). Lane l owns (d=l, d=l+64).
//    Q gets 1/sqrt(D) folded in. Outputs [B][heads][S][D] bf16.
// ---------------------------------------------------------------------------
__global__ __launch_bounds__(256) void norm_rope_kernel(
    const unsigned short* __restrict__ QKVg,
    const float* __restrict__ qw, const float* __restrict__ kw,
    unsigned short* __restrict__ Qr, unsigned short* __restrict__ Kr) {
  const int bs = blockIdx.x;
  const int b = bs >> 11, s = bs & (S_ - 1);
  const int wave = threadIdx.x >> 6, lane = threadIdx.x & 63;

  float invf = 1.0f / powf(10000.0f, (float)lane * (1.0f / 64.0f));
  float sn, cs;
  sincosf((float)s * invf, &sn, &cs);

  const unsigned short* row = QKVg + (size_t)bs * NQKV_;
  const float qwa = qw[lane], qwb = qw[lane + 64];
  const float kwa = kw[lane], kwb = kw[lane + 64];
  const float scale = 0.08838834764831845f;  // 1/sqrt(128)

  for (int h = wave; h < NH_; h += 4) {
    float x0 = bf2f(row[h * D_ + lane]);
    float x1 = bf2f(row[h * D_ + 64 + lane]);
    float ss = x0 * x0 + x1 * x1;
    #pragma unroll
    for (int o = 32; o >= 1; o >>= 1) ss += __shfl_xor(ss, o);
    float r = rsqrtf(ss * (1.0f / 128.0f) + EPS_);
    x0 *= r * qwa; x1 *= r * qwb;
    float o0 = (x0 * cs - x1 * sn) * scale;
    float o1 = (x1 * cs + x0 * sn) * scale;
    size_t off = (((size_t)b * NH_ + h) * S_ + s) * D_;
    Qr[off + lane] = f2bf(o0);
    Qr[off + 64 + lane] = f2bf(o1);
  }
  for (int h = wave; h < NKV_; h += 4) {
    float x0 = bf2f(row[NH_ * D_ + h * D_ + lane]);
    float x1 = bf2f(row[NH_ * D_ + h * D_ + 64 + lane]);
    float ss = x0 * x0 + x1 * x1;
    #pragma unroll
    for (int o = 32; o >= 1; o >>= 1) ss += __shfl_xor(ss, o);
    float r = rsqrtf(ss * (1.0f / 128.0f) + EPS_);
    x0 *= r * kwa; x1 *= r * kwb;
    float o0 = x0 * cs - x1 * sn;
    float o1 = x1 * cs + x0 * sn;
    size_t off = (((size_t)b * NKV_ + h) * S_ + s) * D_;
    Kr[off + lane] = f2bf(o0);
    Kr[off + 64 + lane] = f2bf(o1);
  }
}

// ---------------------------------------------------------------------------
// 5. V transpose: QKVg V-part [b*S+s][hk*128+d] -> Vt[b][hk][d][s]
// ---------------------------------------------------------------------------
__global__ __launch_bounds__(256) void vtrans_kernel(
    const unsigned short* __restrict__ QKVg, unsigned short* __restrict__ Vt) {
  __shared__ unsigned short t[64][65];
  const int s0 = blockIdx.x * 64, d0 = blockIdx.y * 64;
  const int bh = blockIdx.z;  // b*8+hk
  const int b = bh >> 3, hk = bh & 7;
  const int tid = threadIdx.x;
  #pragma unroll
  for (int i = 0; i < 16; ++i) {
    int e = i * 256 + tid; int sr = e >> 6, dc = e & 63;
    t[sr][dc] = QKVg[(size_t)(b * S_ + s0 + sr) * NQKV_ + (NH_ + NKV_) * D_ + hk * D_ + d0 + dc];
  }
  __syncthreads();
  #pragma unroll
  for (int i = 0; i < 16; ++i) {
    int e = i * 256 + tid; int dr = e >> 6, sc = e & 63;
    Vt[((size_t)bh * D_ + d0 + dr) * S_ + s0 + sc] = t[sc][dr];
  }
}

// ---------------------------------------------------------------------------
// 6. Sliding-window flash attention, 8-wave 32x32 structure (R10-proven).
// ---------------------------------------------------------------------------
__global__ __launch_bounds__(512) void attn_kernel(
    const unsigned short* __restrict__ Qr, const unsigned short* __restrict__ Kr,
    const unsigned short* __restrict__ Vt, unsigned short* __restrict__ Out) {
  const int q0 = blockIdx.x * 256;
  const int h = blockIdx.y, b = blockIdx.z, hk = h >> 2;
  const int tid = threadIdx.x;
  const int wave = tid >> 6, lane = tid & 63;
  const int l31 = lane & 31, hi = lane >> 5;
  const int qw0 = q0 + wave * 32;
  const int qpos = qw0 + l31;

  __shared__ __align__(16) unsigned short Ks[64 * 128];  // [kpos][d], swizzled
  __shared__ __align__(16) unsigned short Vs[128 * 64];  // [dout][kpos], swizzled

  bf16x8 qf[8];
  {
    const unsigned short* qp = Qr + (((size_t)b * NH_ + h) * S_ + qpos) * D_ + hi * 8;
    #pragma unroll
    for (int ds = 0; ds < 8; ++ds) qf[ds] = *(const bf16x8*)(qp + ds * 16);
  }

  f32x16 o[4];
  #pragma unroll
  for (int i = 0; i < 4; ++i)
    #pragma unroll
    for (int j = 0; j < 16; ++j) o[i][j] = 0.f;
  float mrun = -1e30f, lrun = 0.f;

  const size_t kbase = ((size_t)b * NKV_ + hk) * S_;
  const size_t vbase = ((size_t)b * NKV_ + hk) * D_;

  const int ktlo = (q0 > 1023) ? ((q0 - 1023) & ~63) : 0;
  const int kthi = (q0 + 255) & ~63;
  const int wlo = (qw0 > 1023) ? ((qw0 - 1023) & ~63) : 0;
  const int whi = (qw0 + 31) & ~63;

  for (int kt = ktlo; kt <= kthi; kt += 64) {
    __syncthreads();  // prior reads complete before overwrite
    #pragma unroll
    for (int it = 0; it < 2; ++it) {
      const int cb = it * 512 + wave * 64;  // wave-uniform chunk base
      const int c = cb + lane;
      const int rk = c >> 4, sk = c & 15;
      gload16(Kr + (kbase + kt + rk) * D_ + ((sk ^ (rk & 7)) * 8), Ks + (size_t)cb * 8);
      const int rv = c >> 3, sv = c & 7;
      gload16(Vt + (vbase + rv) * S_ + kt + ((sv ^ (rv & 7)) * 8), Vs + (size_t)cb * 8);
    }
    __syncthreads();
    if (kt < wlo || kt > whi) continue;  // window skip (barriers already done)

    // ---- S^T = K . Q^T ----
    f32x16 s0, s1;
    #pragma unroll
    for (int j = 0; j < 16; ++j) { s0[j] = 0.f; s1[j] = 0.f; }
    __builtin_amdgcn_s_setprio(1);
    #pragma unroll
    for (int ds = 0; ds < 8; ++ds) {
      const int g = ((ds * 2 + hi) ^ (l31 & 7)) * 8;
      bf16x8 k0 = *(const bf16x8*)&Ks[l31 * 128 + g];
      bf16x8 k1 = *(const bf16x8*)&Ks[(l31 + 32) * 128 + g];
      s0 = __builtin_amdgcn_mfma_f32_32x32x16_bf16(k0, qf[ds], s0, 0, 0, 0);
      s1 = __builtin_amdgcn_mfma_f32_32x32x16_bf16(k1, qf[ds], s1, 0, 0, 0);
    }
    __builtin_amdgcn_s_setprio(0);

    // ---- mask ----
    const bool fullValid = (kt + 63 <= qw0) && (kt >= qw0 - 992);
    if (!fullValid) {
      const int d0 = qpos - kt;
      #pragma unroll
      for (int r = 0; r < 16; ++r) {
        const int koff = (r & 3) + 8 * (r >> 2) + 4 * hi;
        if ((unsigned)(d0 - koff) >= (unsigned)WINDOW_) s0[r] = -1e30f;
        if ((unsigned)(d0 - koff - 32) >= (unsigned)WINDOW_) s1[r] = -1e30f;
      }
    }

    // ---- online softmax with defer-max (T13, THR=8) ----
    float pm = -1e30f;
    #pragma unroll
    for (int r = 0; r < 16; ++r) pm = fmaxf(pm, fmaxf(s0[r], s1[r]));
    pm = fmaxf(pm, __shfl_xor(pm, 32));
    if (!__all(pm - mrun <= 8.f)) {
      const float mnew = fmaxf(mrun, pm);
      const float scl = __expf(mrun - mnew);
      mrun = mnew;
      lrun *= scl;
      #pragma unroll
      for (int i = 0; i < 4; ++i)
        #pragma unroll
        for (int j = 0; j < 16; ++j) o[i][j] *= scl;
    }
    float ts = 0.f;
    #pragma unroll
    for (int r = 0; r < 16; ++r) {
      s0[r] = __expf(s0[r] - mrun); ts += s0[r];
      s1[r] = __expf(s1[r] - mrun); ts += s1[r];
    }
    ts += __shfl_xor(ts, 32);
    lrun += ts;

    // ---- P^T B-frags ----
    unsigned pw[2][2][4];
    #pragma unroll
    for (int t2 = 0; t2 < 2; ++t2) {
      const f32x16 sv = t2 ? s1 : s0;
      #pragma unroll
      for (int sub = 0; sub < 2; ++sub) {
        const int bs4 = sub * 8;
        unsigned A0 = ((unsigned)f2bf(sv[bs4 + 1]) << 16) | f2bf(sv[bs4 + 0]);
        unsigned A1 = ((unsigned)f2bf(sv[bs4 + 3]) << 16) | f2bf(sv[bs4 + 2]);
        unsigned B0 = ((unsigned)f2bf(sv[bs4 + 5]) << 16) | f2bf(sv[bs4 + 4]);
        unsigned B1 = ((unsigned)f2bf(sv[bs4 + 7]) << 16) | f2bf(sv[bs4 + 6]);
        unsigned sA0 = __shfl_xor(A0, 32), sA1 = __shfl_xor(A1, 32);
        unsigned sB0 = __shfl_xor(B0, 32), sB1 = __shfl_xor(B1, 32);
        pw[t2][sub][0] = hi ? sB0 : A0;
        pw[t2][sub][1] = hi ? sB1 : A1;
        pw[t2][sub][2] = hi ? B0 : sA0;
        pw[t2][sub][3] = hi ? B1 : sA1;
      }
    }

    // ---- O^T += V^T . P^T ----
    __builtin_amdgcn_s_setprio(1);
    #pragma unroll
    for (int t2 = 0; t2 < 2; ++t2)
      #pragma unroll
      for (int sub = 0; sub < 2; ++sub) {
        union { unsigned u[4]; bf16x8 v; } pb;
        pb.u[0] = pw[t2][sub][0]; pb.u[1] = pw[t2][sub][1];
        pb.u[2] = pw[t2][sub][2]; pb.u[3] = pw[t2][sub][3];
        #pragma unroll
        for (int dt = 0; dt < 4; ++dt) {
          const int rr = dt * 32 + l31;
          const int g = ((t2 * 4 + sub * 2 + hi) ^ (rr & 7)) * 8;
          bf16x8 vf = *(const bf16x8*)&Vs[rr * 64 + g];
          o[dt] = __builtin_amdgcn_mfma_f32_32x32x16_bf16(vf, pb.v, o[dt], 0, 0, 0);
        }
      }
    __builtin_amdgcn_s_setprio(0);
  }

  // ---- epilogue ----
  const float inv = 1.0f / lrun;
  unsigned short* op = Out + (size_t)(b * S_ + qpos) * (NH_ * D_) + h * D_;
  #pragma unroll
  for (int dt = 0; dt < 4; ++dt)
    #pragma unroll
    for (int g = 0; g < 4; ++g) {
      const int r = g * 4;
      uint2 val;
      val.x = ((unsigned)f2bf(o[dt][r + 1] * inv) << 16) | f2bf(o[dt][r + 0] * inv);
      val.y = ((unsigned)f2bf(o[dt][r + 3] * inv) << 16) | f2bf(o[dt][r + 2] * inv);
      *(uint2*)(op + dt * 32 + 8 * g + 4 * hi) = val;
    }
}

// ---------------------------------------------------------------------------
// Workspace plan (96 MiB of d_ws + d_out as scratch):
//   d_out[ 0,32M): hb (hidden bf16)      — dead after QKV GEMM
//   d_out[32,64M): qr (Q rope)           — dead after attention
//   ws   [ 0,48M): wqkv                  — dead after QKV GEMM, then:
//       ws[ 0, 8M): kr   ws[ 8,16M): vt   ws[16,48M): attn
//   ws   [48,96M): qkvg                  — dead after norm_rope+vtrans, then:
//       ws[48,80M): wot
// ---------------------------------------------------------------------------
extern "C" void kernel_launch(void* const* d_in, const int* in_sizes, int n_in,
                              void* d_out, int out_size, void* d_ws, size_t ws_size,
                              hipStream_t stream) {
  const float* hidden = (const float*)d_in[0];
  const float* wq = (const float*)d_in[1];
  const float* wk = (const float*)d_in[2];
  const float* wv = (const float*)d_in[3];
  const float* wo = (const float*)d_in[4];
  const float* qw = (const float*)d_in[5];
  const float* kw = (const float*)d_in[6];
  float* out = (float*)d_out;

  char* ws = (char*)d_ws;
  unsigned short* wqkv = (unsigned short*)(ws);                       // 48MiB
  unsigned short* kr   = (unsigned short*)(ws);                       //  8MiB (after wqkv dead)
  unsigned short* vt   = (unsigned short*)(ws + ((size_t)8 << 20));   //  8MiB (after wqkv dead)
  unsigned short* attn = (unsigned short*)(ws + ((size_t)16 << 20));  // 32MiB (after wqkv dead)
  unsigned short* qkvg = (unsigned short*)(ws + ((size_t)48 << 20));  // 48MiB
  unsigned short* wot  = (unsigned short*)(ws + ((size_t)48 << 20));  // 32MiB (after qkvg dead)
  unsigned short* hb   = (unsigned short*)d_out;                      // 32MiB
  unsigned short* qr   = (unsigned short*)d_out + ((size_t)16 << 20); // 32MiB

  // 1. weights: transpose+convert into B^T layouts (wq|wk|wv fused)
  transpose_convert<<<dim3(NH_ * D_ / 64, H_ / 64), 256, 0, stream>>>(wq, wqkv, H_, NH_ * D_);
  transpose_convert<<<dim3(NKV_ * D_ / 64, H_ / 64), 256, 0, stream>>>(
      wk, wqkv + (size_t)NH_ * D_ * H_, H_, NKV_ * D_);
  transpose_convert<<<dim3(NKV_ * D_ / 64, H_ / 64), 256, 0, stream>>>(
      wv, wqkv + (size_t)(NH_ + NKV_) * D_ * H_, H_, NKV_ * D_);

  // 2. hidden f32->bf16 (into d_out scratch)
  convert_bf16_kernel<<<(M_ * H_ / 4 + 255) / 256, 256, 0, stream>>>(hidden, hb, M_ * H_ / 4);

  // 3. fused QKV GEMM (2 blocks/CU, single residency round)
  gemm11<true><<<dim3(NQKV_ / 256, M_ / 256), 512, 0, stream>>>(hb, wqkv, qkvg, NQKV_, H_);

  // 4. per-head RMSNorm + RoPE (+1/sqrt(D) on Q); kr overwrites dead wqkv
  norm_rope_kernel<<<M_, 256, 0, stream>>>(qkvg, qw, kw, qr, kr);

  // 5. V transpose to [b][hk][d][s]
  vtrans_kernel<<<dim3(S_ / 64, D_ / 64, B_ * NKV_), 256, 0, stream>>>(qkvg, vt);

  // 6. wo transpose AFTER qkvg is consumed (overwrites dead qkvg region)
  transpose_convert<<<dim3(H_ / 64, H_ / 64), 256, 0, stream>>>(wo, wot, NH_ * D_, H_);

  // 7. sliding-window flash attention -> attn[b*S+s][h*D+d] bf16
  attn_kernel<<<dim3(S_ / 256, NH_, B_), 512, 0, stream>>>(qr, kr, vt, attn);

  // 8. output projection -> f32 d_out (overwrites hb/qr scratch, both dead)
  gemm10<false><<<dim3(H_ / 256, M_ / 256), 512, 0, stream>>>(attn, wot, out, H_, H_);
}

// Round 12
// 511.661 us; speedup vs baseline: 3.5683x; 3.5683x over previous
//
#include <hip/hip_runtime.h>
#include <hip/hip_bf16.h>

#define B_ 2
#define S_ 2048
#define H_ 4096
#define NH_ 32
#define NKV_ 8
#define D_ 128
#define WINDOW_ 1024
#define EPS_ 1e-5f
#define M_ (B_*S_)                       // 4096 rows (b*S+s)
#define NQKV_ ((NH_ + 2*NKV_) * D_)     // 6144

typedef __attribute__((ext_vector_type(8))) __bf16 bf16x8;
typedef __attribute__((ext_vector_type(4))) float f32x4;
typedef __attribute__((ext_vector_type(16))) float f32x16;

__device__ __forceinline__ unsigned short f2bf(float f) {
  union { __hip_bfloat16 h; unsigned short us; } cv;
  cv.h = __float2bfloat16(f);
  return cv.us;
}
__device__ __forceinline__ float bf2f(unsigned short u) {
  union { __hip_bfloat16 h; unsigned short us; } cv;
  cv.us = u;
  return __bfloat162float(cv.h);
}

// async global->LDS, 16B per lane. LDS dest must be wave-uniform base
// (HW adds lane*16); global src is per-lane.
__device__ __forceinline__ void gload16(const unsigned short* g, unsigned short* l) {
  __builtin_amdgcn_global_load_lds(
      (const __attribute__((address_space(1))) unsigned int*)(const void*)g,
      (__attribute__((address_space(3))) unsigned int*)(void*)l, 16, 0, 0);
}

// ---------------------------------------------------------------------------
// 1. Transpose + f32->bf16 convert: in[K][N] f32 -> out[N][K] bf16.
//    64x64 tile: float4 coalesced reads, ushort4 coalesced writes.
// ---------------------------------------------------------------------------
__global__ __launch_bounds__(256) void transpose_convert(
    const float* __restrict__ in, unsigned short* __restrict__ out, int K, int N) {
  __shared__ unsigned short t[64][72];
  const int n0 = blockIdx.x * 64, k0 = blockIdx.y * 64;
  const int tid = threadIdx.x;
  const int rr = tid >> 4, cc = (tid & 15) * 4;
  #pragma unroll
  for (int i = 0; i < 4; ++i) {
    const int r = i * 16 + rr;
    float4 v = *(const float4*)&in[(size_t)(k0 + r) * N + n0 + cc];
    t[cc + 0][r] = f2bf(v.x);
    t[cc + 1][r] = f2bf(v.y);
    t[cc + 2][r] = f2bf(v.z);
    t[cc + 3][r] = f2bf(v.w);
  }
  __syncthreads();
  #pragma unroll
  for (int i = 0; i < 4; ++i) {
    const int r = i * 16 + rr;
    ushort4 o;
    o.x = t[r][cc + 0]; o.y = t[r][cc + 1];
    o.z = t[r][cc + 2]; o.w = t[r][cc + 3];
    *(ushort4*)&out[(size_t)(n0 + r) * K + k0 + cc] = o;
  }
}

// ---------------------------------------------------------------------------
// 2. f32 -> bf16 elementwise (4/thread)
// ---------------------------------------------------------------------------
__global__ __launch_bounds__(256) void convert_bf16_kernel(
    const float* __restrict__ in, unsigned short* __restrict__ out, int n4) {
  int i = blockIdx.x * 256 + threadIdx.x;
  if (i >= n4) return;
  float4 v = ((const float4*)in)[i];
  ushort4 o;
  o.x = f2bf(v.x); o.y = f2bf(v.y); o.z = f2bf(v.z); o.w = f2bf(v.w);
  ((ushort4*)out)[i] = o;
}

// ---------------------------------------------------------------------------
// 3a. QKV GEMM: 256x192 tile (grid 32x16 = 512 blocks = 2 EXACT residency
//     rounds on 256 CUs — kills the 1.5-round tail), 8 waves (2M x 4N, wave
//     tile 128x48), BK=64, gemm10 skeleton verbatim: double-buffered LDS
//     (112KiB), 4-phase interleave, chunk-XOR swizzle (0 conflicts), per-tile
//     own-wave vmcnt(0) gate. C[M][N] = A[M][K] x Bt[N][K], f32 accum.
// ---------------------------------------------------------------------------
template <bool OUT_BF16>
__global__ __launch_bounds__(512) void gemm12(
    const unsigned short* __restrict__ A, const unsigned short* __restrict__ Bt,
    void* __restrict__ Cout, int N, int K) {
  // A: 256*64 = 16384 elem at [0, 16384); B: 192*64 = 12288 at [16384, 28672)
  __shared__ __align__(16) unsigned short lds[2][28672];  // 112 KiB
  const int tid = threadIdx.x;
  const int wave = tid >> 6, lane = tid & 63;
  const int l15 = lane & 15, l16 = lane >> 4;
  const int m0 = blockIdx.y * 256, n0 = blockIdx.x * 192;
  const int wmi = wave >> 2, wni = wave & 3;  // wave -> 128x48 output sub-tile

  const unsigned short* asrc[4];
  const unsigned short* bsrc[3];
  #pragma unroll
  for (int it = 0; it < 4; ++it) {
    const int d = it * 512 + tid;
    const int row = d >> 3, cis = (d & 7) ^ (row & 7);
    asrc[it] = A + (size_t)(m0 + row) * K + cis * 8;
  }
  #pragma unroll
  for (int it = 0; it < 3; ++it) {
    const int d = it * 512 + tid;          // 0..1535, row 0..191
    const int row = d >> 3, cis = (d & 7) ^ (row & 7);
    bsrc[it] = Bt + (size_t)(n0 + row) * K + cis * 8;
  }

  int offA[2][8], offB[2][3];
  #pragma unroll
  for (int kk = 0; kk < 2; ++kk) {
    #pragma unroll
    for (int mi = 0; mi < 8; ++mi) {
      const int row = wmi * 128 + mi * 16 + l15;
      offA[kk][mi] = row * 64 + ((kk * 4 + l16) ^ (row & 7)) * 8;
    }
    #pragma unroll
    for (int ni = 0; ni < 3; ++ni) {
      const int row = wni * 48 + ni * 16 + l15;
      offB[kk][ni] = 16384 + row * 64 + ((kk * 4 + l16) ^ (row & 7)) * 8;
    }
  }

  f32x4 acc[8][3];
  #pragma unroll
  for (int mi = 0; mi < 8; ++mi)
    #pragma unroll
    for (int ni = 0; ni < 3; ++ni) acc[mi][ni] = (f32x4){0.f, 0.f, 0.f, 0.f};

#define PHASE_MFMA(MOFF)                                                     \
  asm volatile("s_waitcnt lgkmcnt(0)" ::: "memory");                         \
  __builtin_amdgcn_sched_barrier(0);                                         \
  __builtin_amdgcn_s_setprio(1);                                             \
  _Pragma("unroll") for (int i = 0; i < 4; ++i)                              \
    _Pragma("unroll") for (int j = 0; j < 3; ++j)                            \
      acc[(MOFF) + i][j] = __builtin_amdgcn_mfma_f32_16x16x32_bf16(          \
          av[i], bv[j], acc[(MOFF) + i][j], 0, 0, 0);                        \
  __builtin_amdgcn_s_setprio(0);                                             \
  __builtin_amdgcn_sched_barrier(0);

  // Prologue: stage tile 0 fully, drain, barrier.
  #pragma unroll
  for (int it = 0; it < 4; ++it)
    gload16(asrc[it], &lds[0][it * 4096 + wave * 512]);
  #pragma unroll
  for (int it = 0; it < 3; ++it)
    gload16(bsrc[it], &lds[0][16384 + it * 4096 + wave * 512]);
  asm volatile("s_waitcnt vmcnt(0)" ::: "memory");
  __builtin_amdgcn_sched_barrier(0);
  __builtin_amdgcn_s_barrier();

  const int nk = K >> 6;
  for (int t = 0; t < nk; ++t) {
    const int cur = t & 1, nxt = cur ^ 1;
    const unsigned short* ldc = lds[cur];
    const bool dostg = (t + 1 < nk);
    const size_t ko = (size_t)(t + 1) * 64;
    bf16x8 av[4], bv[3];

    // ---- phase 0: kk0, M-lo | stage A chunks 0,1 of tile t+1 ----
    #pragma unroll
    for (int i = 0; i < 4; ++i) av[i] = *(const bf16x8*)&ldc[offA[0][i]];
    #pragma unroll
    for (int j = 0; j < 3; ++j) bv[j] = *(const bf16x8*)&ldc[offB[0][j]];
    if (dostg) {
      gload16(asrc[0] + ko, &lds[nxt][0 * 4096 + wave * 512]);
      gload16(asrc[1] + ko, &lds[nxt][1 * 4096 + wave * 512]);
    }
    __builtin_amdgcn_sched_barrier(0);
    __builtin_amdgcn_s_barrier();
    PHASE_MFMA(0)
    __builtin_amdgcn_s_barrier();

    // ---- phase 1: kk0, M-hi (B regs persist) | stage A chunks 2,3 ----
    #pragma unroll
    for (int i = 0; i < 4; ++i) av[i] = *(const bf16x8*)&ldc[offA[0][i + 4]];
    if (dostg) {
      gload16(asrc[2] + ko, &lds[nxt][2 * 4096 + wave * 512]);
      gload16(asrc[3] + ko, &lds[nxt][3 * 4096 + wave * 512]);
    }
    __builtin_amdgcn_sched_barrier(0);
    __builtin_amdgcn_s_barrier();
    PHASE_MFMA(4)
    __builtin_amdgcn_s_barrier();

    // ---- phase 2: kk1, M-lo | stage B chunks 0,1 ----
    #pragma unroll
    for (int i = 0; i < 4; ++i) av[i] = *(const bf16x8*)&ldc[offA[1][i]];
    #pragma unroll
    for (int j = 0; j < 3; ++j) bv[j] = *(const bf16x8*)&ldc[offB[1][j]];
    if (dostg) {
      gload16(bsrc[0] + ko, &lds[nxt][16384 + 0 * 4096 + wave * 512]);
      gload16(bsrc[1] + ko, &lds[nxt][16384 + 1 * 4096 + wave * 512]);
    }
    __builtin_amdgcn_sched_barrier(0);
    __builtin_amdgcn_s_barrier();
    PHASE_MFMA(0)
    __builtin_amdgcn_s_barrier();

    // ---- phase 3: kk1, M-hi | stage B chunk 2 | tile-end gate ----
    #pragma unroll
    for (int i = 0; i < 4; ++i) av[i] = *(const bf16x8*)&ldc[offA[1][i + 4]];
    if (dostg) {
      gload16(bsrc[2] + ko, &lds[nxt][16384 + 2 * 4096 + wave * 512]);
    }
    __builtin_amdgcn_sched_barrier(0);
    __builtin_amdgcn_s_barrier();
    PHASE_MFMA(4)
    asm volatile("s_waitcnt vmcnt(0)" ::: "memory");
    __builtin_amdgcn_sched_barrier(0);
    __builtin_amdgcn_s_barrier();
  }
#undef PHASE_MFMA

  #pragma unroll
  for (int mi = 0; mi < 8; ++mi) {
    #pragma unroll
    for (int ni = 0; ni < 3; ++ni) {
      const int col = n0 + wni * 48 + ni * 16 + l15;
      #pragma unroll
      for (int j = 0; j < 4; ++j) {
        const int row = m0 + wmi * 128 + mi * 16 + l16 * 4 + j;
        if (OUT_BF16)
          ((unsigned short*)Cout)[(size_t)row * N + col] = f2bf(acc[mi][ni][j]);
        else
          ((float*)Cout)[(size_t)row * N + col] = acc[mi][ni][j];
      }
    }
  }
}

// ---------------------------------------------------------------------------
// 3b. Final GEMM (R10-proven, 1 exact round at 256 blocks): 256x256, BK=64,
//     double-buffered 128KiB, 4-phase interleave, chunk-XOR swizzle.
// ---------------------------------------------------------------------------
template <bool OUT_BF16>
__global__ __launch_bounds__(512) void gemm10(
    const unsigned short* __restrict__ A, const unsigned short* __restrict__ Bt,
    void* __restrict__ Cout, int N, int K) {
  __shared__ __align__(16) unsigned short lds[2][2][16384];  // [buf][A/B][256*64] = 128KiB
  const int tid = threadIdx.x;
  const int wave = tid >> 6, lane = tid & 63;
  const int l15 = lane & 15, l16 = lane >> 4;
  const int m0 = blockIdx.y * 256, n0 = blockIdx.x * 256;
  const int wmi = wave >> 2, wni = wave & 3;

  const unsigned short* asrc[4];
  const unsigned short* bsrc[4];
  #pragma unroll
  for (int it = 0; it < 4; ++it) {
    const int d = it * 512 + tid;
    const int row = d >> 3, cis = (d & 7) ^ (row & 7);
    asrc[it] = A + (size_t)(m0 + row) * K + cis * 8;
    bsrc[it] = Bt + (size_t)(n0 + row) * K + cis * 8;
  }

  int offA[2][8], offB[2][4];
  #pragma unroll
  for (int kk = 0; kk < 2; ++kk) {
    #pragma unroll
    for (int mi = 0; mi < 8; ++mi) {
      const int row = wmi * 128 + mi * 16 + l15;
      offA[kk][mi] = row * 64 + ((kk * 4 + l16) ^ (row & 7)) * 8;
    }
    #pragma unroll
    for (int ni = 0; ni < 4; ++ni) {
      const int row = wni * 64 + ni * 16 + l15;
      offB[kk][ni] = row * 64 + ((kk * 4 + l16) ^ (row & 7)) * 8;
    }
  }

  f32x4 acc[8][4];
  #pragma unroll
  for (int mi = 0; mi < 8; ++mi)
    #pragma unroll
    for (int ni = 0; ni < 4; ++ni) acc[mi][ni] = (f32x4){0.f, 0.f, 0.f, 0.f};

#define PHASE_MFMA(MOFF)                                                     \
  asm volatile("s_waitcnt lgkmcnt(0)" ::: "memory");                         \
  __builtin_amdgcn_sched_barrier(0);                                         \
  __builtin_amdgcn_s_setprio(1);                                             \
  _Pragma("unroll") for (int i = 0; i < 4; ++i)                              \
    _Pragma("unroll") for (int j = 0; j < 4; ++j)                            \
      acc[(MOFF) + i][j] = __builtin_amdgcn_mfma_f32_16x16x32_bf16(          \
          av[i], bv[j], acc[(MOFF) + i][j], 0, 0, 0);                        \
  __builtin_amdgcn_s_setprio(0);                                             \
  __builtin_amdgcn_sched_barrier(0);

  #pragma unroll
  for (int it = 0; it < 4; ++it) {
    gload16(asrc[it], &lds[0][0][it * 4096 + wave * 512]);
    gload16(bsrc[it], &lds[0][1][it * 4096 + wave * 512]);
  }
  asm volatile("s_waitcnt vmcnt(0)" ::: "memory");
  __builtin_amdgcn_sched_barrier(0);
  __builtin_amdgcn_s_barrier();

  const int nk = K >> 6;
  for (int t = 0; t < nk; ++t) {
    const int cur = t & 1, nxt = cur ^ 1;
    const unsigned short* as = lds[cur][0];
    const unsigned short* bs = lds[cur][1];
    const bool dostg = (t + 1 < nk);
    const size_t ko = (size_t)(t + 1) * 64;
    bf16x8 av[4], bv[4];

    #pragma unroll
    for (int i = 0; i < 4; ++i) av[i] = *(const bf16x8*)&as[offA[0][i]];
    #pragma unroll
    for (int j = 0; j < 4; ++j) bv[j] = *(const bf16x8*)&bs[offB[0][j]];
    if (dostg) {
      gload16(asrc[0] + ko, &lds[nxt][0][0 * 4096 + wave * 512]);
      gload16(asrc[1] + ko, &lds[nxt][0][1 * 4096 + wave * 512]);
    }
    __builtin_amdgcn_sched_barrier(0);
    __builtin_amdgcn_s_barrier();
    PHASE_MFMA(0)
    __builtin_amdgcn_s_barrier();

    #pragma unroll
    for (int i = 0; i < 4; ++i) av[i] = *(const bf16x8*)&as[offA[0][i + 4]];
    if (dostg) {
      gload16(asrc[2] + ko, &lds[nxt][0][2 * 4096 + wave * 512]);
      gload16(asrc[3] + ko, &lds[nxt][0][3 * 4096 + wave * 512]);
    }
    __builtin_amdgcn_sched_barrier(0);
    __builtin_amdgcn_s_barrier();
    PHASE_MFMA(4)
    __builtin_amdgcn_s_barrier();

    #pragma unroll
    for (int i = 0; i < 4; ++i) av[i] = *(const bf16x8*)&as[offA[1][i]];
    #pragma unroll
    for (int j = 0; j < 4; ++j) bv[j] = *(const bf16x8*)&bs[offB[1][j]];
    if (dostg) {
      gload16(bsrc[0] + ko, &lds[nxt][1][0 * 4096 + wave * 512]);
      gload16(bsrc[1] + ko, &lds[nxt][1][1 * 4096 + wave * 512]);
    }
    __builtin_amdgcn_sched_barrier(0);
    __builtin_amdgcn_s_barrier();
    PHASE_MFMA(0)
    __builtin_amdgcn_s_barrier();

    #pragma unroll
    for (int i = 0; i < 4; ++i) av[i] = *(const bf16x8*)&as[offA[1][i + 4]];
    if (dostg) {
      gload16(bsrc[2] + ko, &lds[nxt][1][2 * 4096 + wave * 512]);
      gload16(bsrc[3] + ko, &lds[nxt][1][3 * 4096 + wave * 512]);
    }
    __builtin_amdgcn_sched_barrier(0);
    __builtin_amdgcn_s_barrier();
    PHASE_MFMA(4)
    asm volatile("s_waitcnt vmcnt(0)" ::: "memory");
    __builtin_amdgcn_sched_barrier(0);
    __builtin_amdgcn_s_barrier();
  }
#undef PHASE_MFMA

  #pragma unroll
  for (int mi = 0; mi < 8; ++mi) {
    #pragma unroll
    for (int ni = 0; ni < 4; ++ni) {
      const int col = n0 + wni * 64 + ni * 16 + l15;
      #pragma unroll
      for (int j = 0; j < 4; ++j) {
        const int row = m0 + wmi * 128 + mi * 16 + l16 * 4 + j;
        if (OUT_BF16)
          ((unsigned short*)Cout)[(size_t)row * N + col] = f2bf(acc[mi][ni][j]);
        else
          ((float*)Cout)[(size_t)row * N + col] = acc[mi][ni][j];
      }
    }
  }
}

// ---------------------------------------------------------------------------
// 4. Per-head RMSNorm + RoPE. One block per (b,s). Lane l owns (d=l, d=l+64).
//    Q gets 1/sqrt(D) folded in. Outputs [B][heads][S][D] bf16.
// ---------------------------------------------------------------------------
__global__ __launch_bounds__(256) void norm_rope_kernel(
    const unsigned short* __restrict__ QKVg,
    const float* __restrict__ qw, const float* __restrict__ kw,
    unsigned short* __restrict__ Qr, unsigned short* __restrict__ Kr) {
  const int bs = blockIdx.x;
  const int b = bs >> 11, s = bs & (S_ - 1);
  const int wave = threadIdx.x >> 6, lane = threadIdx.x & 63;

  float invf = 1.0f / powf(10000.0f, (float)lane * (1.0f / 64.0f));
  float sn, cs;
  sincosf((float)s * invf, &sn, &cs);

  const unsigned short* row = QKVg + (size_t)bs * NQKV_;
  const float qwa = qw[lane], qwb = qw[lane + 64];
  const float kwa = kw[lane], kwb = kw[lane + 64];
  const float scale = 0.08838834764831845f;  // 1/sqrt(128)

  for (int h = wave; h < NH_; h += 4) {
    float x0 = bf2f(row[h * D_ + lane]);
    float x1 = bf2f(row[h * D_ + 64 + lane]);
    float ss = x0 * x0 + x1 * x1;
    #pragma unroll
    for (int o = 32; o >= 1; o >>= 1) ss += __shfl_xor(ss, o);
    float r = rsqrtf(ss * (1.0f / 128.0f) + EPS_);
    x0 *= r * qwa; x1 *= r * qwb;
    float o0 = (x0 * cs - x1 * sn) * scale;
    float o1 = (x1 * cs + x0 * sn) * scale;
    size_t off = (((size_t)b * NH_ + h) * S_ + s) * D_;
    Qr[off + lane] = f2bf(o0);
    Qr[off + 64 + lane] = f2bf(o1);
  }
  for (int h = wave; h < NKV_; h += 4) {
    float x0 = bf2f(row[NH_ * D_ + h * D_ + lane]);
    float x1 = bf2f(row[NH_ * D_ + h * D_ + 64 + lane]);
    float ss = x0 * x0 + x1 * x1;
    #pragma unroll
    for (int o = 32; o >= 1; o >>= 1) ss += __shfl_xor(ss, o);
    float r = rsqrtf(ss * (1.0f / 128.0f) + EPS_);
    x0 *= r * kwa; x1 *= r * kwb;
    float o0 = x0 * cs - x1 * sn;
    float o1 = x1 * cs + x0 * sn;
    size_t off = (((size_t)b * NKV_ + h) * S_ + s) * D_;
    Kr[off + lane] = f2bf(o0);
    Kr[off + 64 + lane] = f2bf(o1);
  }
}

// ---------------------------------------------------------------------------
// 5. V transpose: QKVg V-part [b*S+s][hk*128+d] -> Vt[b][hk][d][s]
// ---------------------------------------------------------------------------
__global__ __launch_bounds__(256) void vtrans_kernel(
    const unsigned short* __restrict__ QKVg, unsigned short* __restrict__ Vt) {
  __shared__ unsigned short t[64][65];
  const int s0 = blockIdx.x * 64, d0 = blockIdx.y * 64;
  const int bh = blockIdx.z;  // b*8+hk
  const int b = bh >> 3, hk = bh & 7;
  const int tid = threadIdx.x;
  #pragma unroll
  for (int i = 0; i < 16; ++i) {
    int e = i * 256 + tid; int sr = e >> 6, dc = e & 63;
    t[sr][dc] = QKVg[(size_t)(b * S_ + s0 + sr) * NQKV_ + (NH_ + NKV_) * D_ + hk * D_ + d0 + dc];
  }
  __syncthreads();
  #pragma unroll
  for (int i = 0; i < 16; ++i) {
    int e = i * 256 + tid; int dr = e >> 6, sc = e & 63;
    Vt[((size_t)bh * D_ + d0 + dr) * S_ + s0 + sc] = t[sc][dr];
  }
}

// ---------------------------------------------------------------------------
// 6. Sliding-window flash attention, 8-wave 32x32 structure (R10-proven).
// ---------------------------------------------------------------------------
__global__ __launch_bounds__(512) void attn_kernel(
    const unsigned short* __restrict__ Qr, const unsigned short* __restrict__ Kr,
    const unsigned short* __restrict__ Vt, unsigned short* __restrict__ Out) {
  const int q0 = blockIdx.x * 256;
  const int h = blockIdx.y, b = blockIdx.z, hk = h >> 2;
  const int tid = threadIdx.x;
  const int wave = tid >> 6, lane = tid & 63;
  const int l31 = lane & 31, hi = lane >> 5;
  const int qw0 = q0 + wave * 32;
  const int qpos = qw0 + l31;

  __shared__ __align__(16) unsigned short Ks[64 * 128];  // [kpos][d], swizzled
  __shared__ __align__(16) unsigned short Vs[128 * 64];  // [dout][kpos], swizzled

  bf16x8 qf[8];
  {
    const unsigned short* qp = Qr + (((size_t)b * NH_ + h) * S_ + qpos) * D_ + hi * 8;
    #pragma unroll
    for (int ds = 0; ds < 8; ++ds) qf[ds] = *(const bf16x8*)(qp + ds * 16);
  }

  f32x16 o[4];
  #pragma unroll
  for (int i = 0; i < 4; ++i)
    #pragma unroll
    for (int j = 0; j < 16; ++j) o[i][j] = 0.f;
  float mrun = -1e30f, lrun = 0.f;

  const size_t kbase = ((size_t)b * NKV_ + hk) * S_;
  const size_t vbase = ((size_t)b * NKV_ + hk) * D_;

  const int ktlo = (q0 > 1023) ? ((q0 - 1023) & ~63) : 0;
  const int kthi = (q0 + 255) & ~63;
  const int wlo = (qw0 > 1023) ? ((qw0 - 1023) & ~63) : 0;
  const int whi = (qw0 + 31) & ~63;

  for (int kt = ktlo; kt <= kthi; kt += 64) {
    __syncthreads();  // prior reads complete before overwrite
    #pragma unroll
    for (int it = 0; it < 2; ++it) {
      const int cb = it * 512 + wave * 64;  // wave-uniform chunk base
      const int c = cb + lane;
      const int rk = c >> 4, sk = c & 15;
      gload16(Kr + (kbase + kt + rk) * D_ + ((sk ^ (rk & 7)) * 8), Ks + (size_t)cb * 8);
      const int rv = c >> 3, sv = c & 7;
      gload16(Vt + (vbase + rv) * S_ + kt + ((sv ^ (rv & 7)) * 8), Vs + (size_t)cb * 8);
    }
    __syncthreads();
    if (kt < wlo || kt > whi) continue;  // window skip (barriers already done)

    // ---- S^T = K . Q^T ----
    f32x16 s0, s1;
    #pragma unroll
    for (int j = 0; j < 16; ++j) { s0[j] = 0.f; s1[j] = 0.f; }
    __builtin_amdgcn_s_setprio(1);
    #pragma unroll
    for (int ds = 0; ds < 8; ++ds) {
      const int g = ((ds * 2 + hi) ^ (l31 & 7)) * 8;
      bf16x8 k0 = *(const bf16x8*)&Ks[l31 * 128 + g];
      bf16x8 k1 = *(const bf16x8*)&Ks[(l31 + 32) * 128 + g];
      s0 = __builtin_amdgcn_mfma_f32_32x32x16_bf16(k0, qf[ds], s0, 0, 0, 0);
      s1 = __builtin_amdgcn_mfma_f32_32x32x16_bf16(k1, qf[ds], s1, 0, 0, 0);
    }
    __builtin_amdgcn_s_setprio(0);

    // ---- mask ----
    const bool fullValid = (kt + 63 <= qw0) && (kt >= qw0 - 992);
    if (!fullValid) {
      const int d0 = qpos - kt;
      #pragma unroll
      for (int r = 0; r < 16; ++r) {
        const int koff = (r & 3) + 8 * (r >> 2) + 4 * hi;
        if ((unsigned)(d0 - koff) >= (unsigned)WINDOW_) s0[r] = -1e30f;
        if ((unsigned)(d0 - koff - 32) >= (unsigned)WINDOW_) s1[r] = -1e30f;
      }
    }

    // ---- online softmax with defer-max (T13, THR=8) ----
    float pm = -1e30f;
    #pragma unroll
    for (int r = 0; r < 16; ++r) pm = fmaxf(pm, fmaxf(s0[r], s1[r]));
    pm = fmaxf(pm, __shfl_xor(pm, 32));
    if (!__all(pm - mrun <= 8.f)) {
      const float mnew = fmaxf(mrun, pm);
      const float scl = __expf(mrun - mnew);
      mrun = mnew;
      lrun *= scl;
      #pragma unroll
      for (int i = 0; i < 4; ++i)
        #pragma unroll
        for (int j = 0; j < 16; ++j) o[i][j] *= scl;
    }
    float ts = 0.f;
    #pragma unroll
    for (int r = 0; r < 16; ++r) {
      s0[r] = __expf(s0[r] - mrun); ts += s0[r];
      s1[r] = __expf(s1[r] - mrun); ts += s1[r];
    }
    ts += __shfl_xor(ts, 32);
    lrun += ts;

    // ---- P^T B-frags ----
    unsigned pw[2][2][4];
    #pragma unroll
    for (int t2 = 0; t2 < 2; ++t2) {
      const f32x16 sv = t2 ? s1 : s0;
      #pragma unroll
      for (int sub = 0; sub < 2; ++sub) {
        const int bs4 = sub * 8;
        unsigned A0 = ((unsigned)f2bf(sv[bs4 + 1]) << 16) | f2bf(sv[bs4 + 0]);
        unsigned A1 = ((unsigned)f2bf(sv[bs4 + 3]) << 16) | f2bf(sv[bs4 + 2]);
        unsigned B0 = ((unsigned)f2bf(sv[bs4 + 5]) << 16) | f2bf(sv[bs4 + 4]);
        unsigned B1 = ((unsigned)f2bf(sv[bs4 + 7]) << 16) | f2bf(sv[bs4 + 6]);
        unsigned sA0 = __shfl_xor(A0, 32), sA1 = __shfl_xor(A1, 32);
        unsigned sB0 = __shfl_xor(B0, 32), sB1 = __shfl_xor(B1, 32);
        pw[t2][sub][0] = hi ? sB0 : A0;
        pw[t2][sub][1] = hi ? sB1 : A1;
        pw[t2][sub][2] = hi ? B0 : sA0;
        pw[t2][sub][3] = hi ? B1 : sA1;
      }
    }

    // ---- O^T += V^T . P^T ----
    __builtin_amdgcn_s_setprio(1);
    #pragma unroll
    for (int t2 = 0; t2 < 2; ++t2)
      #pragma unroll
      for (int sub = 0; sub < 2; ++sub) {
        union { unsigned u[4]; bf16x8 v; } pb;
        pb.u[0] = pw[t2][sub][0]; pb.u[1] = pw[t2][sub][1];
        pb.u[2] = pw[t2][sub][2]; pb.u[3] = pw[t2][sub][3];
        #pragma unroll
        for (int dt = 0; dt < 4; ++dt) {
          const int rr = dt * 32 + l31;
          const int g = ((t2 * 4 + sub * 2 + hi) ^ (rr & 7)) * 8;
          bf16x8 vf = *(const bf16x8*)&Vs[rr * 64 + g];
          o[dt] = __builtin_amdgcn_mfma_f32_32x32x16_bf16(vf, pb.v, o[dt], 0, 0, 0);
        }
      }
    __builtin_amdgcn_s_setprio(0);
  }

  // ---- epilogue ----
  const float inv = 1.0f / lrun;
  unsigned short* op = Out + (size_t)(b * S_ + qpos) * (NH_ * D_) + h * D_;
  #pragma unroll
  for (int dt = 0; dt < 4; ++dt)
    #pragma unroll
    for (int g = 0; g < 4; ++g) {
      const int r = g * 4;
      uint2 val;
      val.x = ((unsigned)f2bf(o[dt][r + 1] * inv) << 16) | f2bf(o[dt][r + 0] * inv);
      val.y = ((unsigned)f2bf(o[dt][r + 3] * inv) << 16) | f2bf(o[dt][r + 2] * inv);
      *(uint2*)(op + dt * 32 + 8 * g + 4 * hi) = val;
    }
}

// ---------------------------------------------------------------------------
// Workspace plan (96 MiB of d_ws + d_out as scratch):
//   d_out[ 0,32M): hb (hidden bf16)      — dead after QKV GEMM
//   d_out[32,64M): qr (Q rope)           — dead after attention
//   ws   [ 0,48M): wqkv                  — dead after QKV GEMM, then:
//       ws[ 0, 8M): kr   ws[ 8,16M): vt   ws[16,48M): attn
//   ws   [48,96M): qkvg                  — dead after norm_rope+vtrans, then:
//       ws[48,80M): wot
// ---------------------------------------------------------------------------
extern "C" void kernel_launch(void* const* d_in, const int* in_sizes, int n_in,
                              void* d_out, int out_size, void* d_ws, size_t ws_size,
                              hipStream_t stream) {
  const float* hidden = (const float*)d_in[0];
  const float* wq = (const float*)d_in[1];
  const float* wk = (const float*)d_in[2];
  const float* wv = (const float*)d_in[3];
  const float* wo = (const float*)d_in[4];
  const float* qw = (const float*)d_in[5];
  const float* kw = (const float*)d_in[6];
  float* out = (float*)d_out;

  char* ws = (char*)d_ws;
  unsigned short* wqkv = (unsigned short*)(ws);                       // 48MiB
  unsigned short* kr   = (unsigned short*)(ws);                       //  8MiB (after wqkv dead)
  unsigned short* vt   = (unsigned short*)(ws + ((size_t)8 << 20));   //  8MiB (after wqkv dead)
  unsigned short* attn = (unsigned short*)(ws + ((size_t)16 << 20));  // 32MiB (after wqkv dead)
  unsigned short* qkvg = (unsigned short*)(ws + ((size_t)48 << 20));  // 48MiB
  unsigned short* wot  = (unsigned short*)(ws + ((size_t)48 << 20));  // 32MiB (after qkvg dead)
  unsigned short* hb   = (unsigned short*)d_out;                      // 32MiB
  unsigned short* qr   = (unsigned short*)d_out + ((size_t)16 << 20); // 32MiB

  // 1. weights: transpose+convert into B^T layouts (wq|wk|wv fused)
  transpose_convert<<<dim3(NH_ * D_ / 64, H_ / 64), 256, 0, stream>>>(wq, wqkv, H_, NH_ * D_);
  transpose_convert<<<dim3(NKV_ * D_ / 64, H_ / 64), 256, 0, stream>>>(
      wk, wqkv + (size_t)NH_ * D_ * H_, H_, NKV_ * D_);
  transpose_convert<<<dim3(NKV_ * D_ / 64, H_ / 64), 256, 0, stream>>>(
      wv, wqkv + (size_t)(NH_ + NKV_) * D_ * H_, H_, NKV_ * D_);

  // 2. hidden f32->bf16 (into d_out scratch)
  convert_bf16_kernel<<<(M_ * H_ / 4 + 255) / 256, 256, 0, stream>>>(hidden, hb, M_ * H_ / 4);

  // 3. fused QKV GEMM: 256x192 tiles -> 512 blocks = 2 exact rounds
  gemm12<true><<<dim3(NQKV_ / 192, M_ / 256), 512, 0, stream>>>(hb, wqkv, qkvg, NQKV_, H_);

  // 4. per-head RMSNorm + RoPE (+1/sqrt(D) on Q); kr overwrites dead wqkv
  norm_rope_kernel<<<M_, 256, 0, stream>>>(qkvg, qw, kw, qr, kr);

  // 5. V transpose to [b][hk][d][s]
  vtrans_kernel<<<dim3(S_ / 64, D_ / 64, B_ * NKV_), 256, 0, stream>>>(qkvg, vt);

  // 6. wo transpose AFTER qkvg is consumed (overwrites dead qkvg region)
  transpose_convert<<<dim3(H_ / 64, H_ / 64), 256, 0, stream>>>(wo, wot, NH_ * D_, H_);

  // 7. sliding-window flash attention -> attn[b*S+s][h*D+d] bf16
  attn_kernel<<<dim3(S_ / 256, NH_, B_), 512, 0, stream>>>(qr, kr, vt, attn);

  // 8. output projection -> f32 d_out (overwrites hb/qr scratch, both dead)
  gemm10<false><<<dim3(H_ / 256, M_ / 256), 512, 0, stream>>>(attn, wot, out, H_, H_);
}